// Round 10
// baseline (44.892 us; speedup 1.0000x reference)
//
#include <hip/hip_runtime.h>

#define NB 32
#define TLEN 480000
#define NF 1876                    // (480000 + 2*512 - 1024)/256 + 1
#define FSTRIP 16                  // frames per wave (strip)
#define WPR 118                    // ceil(NF/FSTRIP)
#define WTHREADS 256

// ---- DPP-based wave reduction: 4 VALU dpp-adds + 2 cross-row shuffles ----
template <int CTRL>
__device__ __forceinline__ float dpp_add(float x) {
    int y = __builtin_amdgcn_update_dpp(0, __float_as_int(x), CTRL, 0xF, 0xF, true);
    return x + __int_as_float(y);
}

__device__ __forceinline__ float wave_reduce(float s) {
    s = dpp_add<0xB1>(s);   // quad_perm(1,0,3,2) : xor1
    s = dpp_add<0x4E>(s);   // quad_perm(2,3,0,1) : xor2
    s = dpp_add<0x124>(s);  // row_ror:4
    s = dpp_add<0x128>(s);  // row_ror:8
    s += __shfl_xor(s, 16);
    s += __shfl_xor(s, 32);
    return s;
}

__device__ __forceinline__ float f4c(const float4& v, int j) {
    return j == 0 ? v.x : (j == 1 ? v.y : (j == 2 ? v.z : v.w));
}

// fast squared periodic-Hann: w = 0.5 - 0.5*cos(2*pi*p/1024), via v_cos_f32
__device__ __forceinline__ float w2fast(float p) {
    float w = 0.5f - 0.5f * __cosf(p * (6.28318530717958647692f / 1024.0f));
    return w * w;
}

// ---- kernel 1: 16-frame persistent strips, group-prefetched window ------
// Strip wv covers frames [16wv, 16wv+16); blocks m=0..18 are 256-sample
// spans starting at sample 4096wv-512+256m; float4 idx = 1024wv-128+64m+lane.
// mod-11 register window; loads >= 1 group (~1700cy) ahead of use.
// ALL global stores happen after ALL loads (vmcnt queue stays load-only).
__global__ __launch_bounds__(WTHREADS, 2) void seg_frames(
    const float* __restrict__ est, const float* __restrict__ tgt,
    float* __restrict__ ws_part, float* __restrict__ ws_bs)
{
    const int tid  = threadIdx.x;
    const int lane = tid & 63;
    const int wave = tid >> 6;
    const int b    = blockIdx.y;
    const int wv   = blockIdx.x * 4 + wave;
    if (wv >= WPR) return;
    const int fb = wv * FSTRIP;

    const float* erow = est + (size_t)b * TLEN;
    const float* trow = tgt + (size_t)b * TLEN;

    float pe = 0.f, pt = 0.f;      // plain sums over owned samples (means)

    if (wv >= 1 && wv <= 116) {
        // ================= fast path (all 16 frames interior) ============
        const float4* e4 = (const float4*)erow;
        const float4* t4 = (const float4*)trow;
        const int gbase = 1024 * wv - 128 + lane;

        // prologue: blocks 0..10 (covers groups 0 and 1) — 22 loads in flight
        float4 E[11], T[11];
#pragma unroll
        for (int m = 0; m < 11; ++m) {
            E[m] = e4[gbase + 64 * m];
            T[m] = t4[gbase + 64 * m];
        }

        // w^2 at positions p = 256q + 4*lane + j  (hidden under load latency)
        float w2v[4][4];
#pragma unroll
        for (int q = 0; q < 4; ++q)
#pragma unroll
            for (int j = 0; j < 4; ++j)
                w2v[q][j] = w2fast((float)(256 * q + 4 * lane + j));

        float vres[FSTRIP];        // packed per-frame results (lanes 0..4)

#pragma unroll
        for (int gq = 0; gq < 4; ++gq) {
            // group-prefetch: issue next group's missing blocks one group early
            if (gq == 1) {
#pragma unroll
                for (int m = 11; m < 15; ++m) {      // slots 0..3 (blocks 0..3 dead)
                    E[m - 11] = e4[gbase + 64 * m];
                    T[m - 11] = t4[gbase + 64 * m];
                }
            }
            if (gq == 2) {
#pragma unroll
                for (int m = 15; m < 19; ++m) {      // slots 4..7 (blocks 4..7 dead)
                    E[m - 11] = e4[gbase + 64 * m];
                    T[m - 11] = t4[gbase + 64 * m];
                }
            }

            float acc[4][5];
#pragma unroll
            for (int i = 0; i < 4; ++i)
#pragma unroll
                for (int s5 = 0; s5 < 5; ++s5) acc[i][s5] = 0.f;

            // hop-major over this group's 7 blocks
#pragma unroll
            for (int k = 0; k < 7; ++k) {
                const int slot = (4 * gq + k) % 11;  // compile-time
                float4 ev4 = E[slot], tv4 = T[slot];
#pragma unroll
                for (int j = 0; j < 4; ++j) {
                    float e = f4c(ev4, j), t = f4c(tv4, j);
                    float et = e * t, tt2 = t * t, ee2 = e * e;
#pragma unroll
                    for (int i = 0; i < 4; ++i) {
                        if (k - i < 0 || k - i > 3) continue;   // const-folds
                        float w2 = w2v[k - i][j];
                        acc[i][0] = fmaf(w2, et,  acc[i][0]);
                        acc[i][1] = fmaf(w2, tt2, acc[i][1]);
                        acc[i][2] = fmaf(w2, ee2, acc[i][2]);
                        acc[i][3] = fmaf(w2, e,   acc[i][3]);
                        acc[i][4] = fmaf(w2, t,   acc[i][4]);
                    }
                }
                if (k >= 2 && k <= 5) {  // blocks 2..17 across groups: owned hops
                    pe += (ev4.x + ev4.y) + (ev4.z + ev4.w);
                    pt += (tv4.x + tv4.y) + (tv4.z + tv4.w);
                }
            }

            // reduce + pack into one register per frame (no vmem stores here)
#pragma unroll
            for (int i = 0; i < 4; ++i) {
                float s0 = wave_reduce(acc[i][0]);
                float s1 = wave_reduce(acc[i][1]);
                float s2 = wave_reduce(acc[i][2]);
                float s3 = wave_reduce(acc[i][3]);
                float s4 = wave_reduce(acc[i][4]);
                float v = s0;
                v = (lane == 1) ? s1 : v;
                v = (lane == 2) ? s2 : v;
                v = (lane == 3) ? s3 : v;
                v = (lane == 4) ? s4 : v;
                vres[4 * gq + i] = v;
            }
        }

        // epilogue: all stores after all loads (lanes 0..4, 20B/frame, contiguous)
        if (lane < 5) {
            float* pbase = ws_part + (size_t)(b * NF + fb) * 5 + lane;
#pragma unroll
            for (int fi = 0; fi < FSTRIP; ++fi)
                pbase[fi * 5] = vres[fi];
        }
    } else {
        // ================= edge path (wv==0 or wv==117) ==================
        int nfr = NF - fb;
        if (nfr > FSTRIP) nfr = FSTRIP;

        float w2v[4][4];
#pragma unroll
        for (int q = 0; q < 4; ++q)
#pragma unroll
            for (int j = 0; j < 4; ++j)
                w2v[q][j] = w2fast((float)(256 * q + 4 * lane + j));

        for (int i = 0; i < nfr; ++i) {
            int f = fb + i;
            float s_et = 0.f, s_tt = 0.f, s_ee = 0.f, s_e = 0.f, s_t = 0.f;
#pragma unroll
            for (int q = 0; q < 4; ++q)
#pragma unroll
                for (int j = 0; j < 4; ++j) {
                    int s = 256 * f - 512 + 256 * q + 4 * lane + j;
                    int idx = s < 0 ? -s : (s >= TLEN ? 2 * (TLEN - 1) - s : s);
                    float ev = erow[idx], tv = trow[idx];
                    float w2 = w2v[q][j];
                    float et = ev * tv;
                    s_et = fmaf(w2, et,      s_et);
                    s_tt = fmaf(w2, tv * tv, s_tt);
                    s_ee = fmaf(w2, ev * ev, s_ee);
                    s_e  = fmaf(w2, ev, s_e);
                    s_t  = fmaf(w2, tv, s_t);
                }
            s_et = wave_reduce(s_et);
            s_tt = wave_reduce(s_tt);
            s_ee = wave_reduce(s_ee);
            s_e  = wave_reduce(s_e);
            s_t  = wave_reduce(s_t);
            if (lane == 0) {
                float* p = ws_part + (size_t)(b * NF + f) * 5;
                p[0] = s_et; p[1] = s_tt; p[2] = s_ee; p[3] = s_e; p[4] = s_t;
            }
        }

        // owned samples for the means (disjoint from fast strips' coverage)
        const float4* e4 = (const float4*)erow;
        const float4* t4 = (const float4*)trow;
        if (fb == 0) {
            // own [0, 4096): 1024 float4, 16 per lane
#pragma unroll
            for (int k = 0; k < 16; ++k) {
                float4 ev4 = e4[lane + 64 * k];
                float4 tv4 = t4[lane + 64 * k];
                pe += (ev4.x + ev4.y) + (ev4.z + ev4.w);
                pt += (tv4.x + tv4.y) + (tv4.z + tv4.w);
            }
        } else {
            // own [479232, 480000): 192 float4, 3 per lane
#pragma unroll
            for (int k = 0; k < 3; ++k) {
                int g = 119808 + lane + 64 * k;
                float4 ev4 = e4[g];
                float4 tv4 = t4[g];
                pe += (ev4.x + ev4.y) + (ev4.z + ev4.w);
                pt += (tv4.x + tv4.y) + (tv4.z + tv4.w);
            }
        }
    }

    // per-wave plain-sum partials -> workspace (for the row means)
    pe = wave_reduce(pe);
    pt = wave_reduce(pt);
    if (lane == 0) {
        ws_bs[(0 * NB + b) * WPR + wv] = pe;
        ws_bs[(1 * NB + b) * WPR + wv] = pt;
    }
}

// ------ kernel 2 (fused): recompute row means per block + final loss ------
__global__ __launch_bounds__(WTHREADS) void seg_final(
    const float* __restrict__ ws_part, const float* __restrict__ ws_bs,
    float* __restrict__ out)
{
    const int tid  = threadIdx.x;
    const int lane = tid & 63;
    const int wave = tid >> 6;
    const int idx0 = blockIdx.x * WTHREADS;

    // block spans at most 2 batch rows; 4 waves reduce (sig in {e,t}) x {b0,b1}
    int b0 = idx0 / NF;
    int ilast = idx0 + WTHREADS - 1;
    if (ilast > NB * NF - 1) ilast = NB * NF - 1;
    int b1 = ilast / NF;

    __shared__ float smean[4];   // [which*2 + sig]
    {
        int sig = wave & 1;
        int row = (wave >> 1) ? b1 : b0;
        const float* pbs = ws_bs + (size_t)(sig * NB + row) * WPR;
        float s = 0.f;
        for (int c = lane; c < WPR; c += 64) s += pbs[c];   // 2 iters, L2-hot
        s = wave_reduce(s);
        if (lane == 0) smean[wave] = s * (1.0f / (float)TLEN);
    }
    __syncthreads();

    int idx = idx0 + tid;
    if (idx >= NB * NF) return;
    int b = idx / NF;
    int which = (b == b0) ? 0 : 1;
    float me = smean[which * 2 + 0];
    float mt = smean[which * 2 + 1];

    const float* p = ws_part + (size_t)idx * 5;
    float S_et = p[0], S_tt = p[1], S_ee = p[2], S_e = p[3], S_t = p[4];
    const float W2 = 384.0f;         // sum of squared periodic Hann, exact

    float dot = S_et - mt * S_e - me * S_t + me * mt * W2;
    float tt  = S_tt - 2.0f * mt * S_t + mt * mt * W2;
    float ee  = S_ee - 2.0f * me * S_e + me * me * W2;

    float a     = dot / (tt + 1e-8f);
    float st2   = a * a * tt;
    float en2   = ee - 2.0f * a * dot + st2;
    float ratio = st2 / (en2 + 1e-8f);
    out[idx] = -10.0f * log10f(ratio + 1e-8f);
}

extern "C" void kernel_launch(void* const* d_in, const int* in_sizes, int n_in,
                              void* d_out, int out_size, void* d_ws, size_t ws_size,
                              hipStream_t stream)
{
    const float* est = (const float*)d_in[0];
    const float* tgt = (const float*)d_in[1];
    float* out = (float*)d_out;

    float* ws      = (float*)d_ws;
    float* ws_part = ws;                                   // NB*NF*5   floats
    float* ws_bs   = ws_part + (size_t)NB * NF * 5;        // 2*NB*WPR  floats

    dim3 grid1((WPR + 3) / 4, NB);
    seg_frames<<<grid1, WTHREADS, 0, stream>>>(est, tgt, ws_part, ws_bs);
    dim3 grid2((NB * NF + WTHREADS - 1) / WTHREADS);
    seg_final<<<grid2, WTHREADS, 0, stream>>>(ws_part, ws_bs, out);
}

// Round 11
// 35.497 us; speedup vs baseline: 1.2646x; 1.2646x over previous
//
#include <hip/hip_runtime.h>

#define NB 32
#define TLEN 480000
#define NF 1876                    // (480000 + 2*512 - 1024)/256 + 1
#define FR 4                       // frames per wave
#define WPR 469                    // ceil(NF/FR) waves per row
#define WTHREADS 256

// ---- DPP-based wave reduction: 4 VALU dpp-adds + 2 cross-row shuffles ----
template <int CTRL>
__device__ __forceinline__ float dpp_add(float x) {
    int y = __builtin_amdgcn_update_dpp(0, __float_as_int(x), CTRL, 0xF, 0xF, true);
    return x + __int_as_float(y);
}

__device__ __forceinline__ float wave_reduce(float s) {
    s = dpp_add<0xB1>(s);   // quad_perm(1,0,3,2) : xor1
    s = dpp_add<0x4E>(s);   // quad_perm(2,3,0,1) : xor2
    s = dpp_add<0x124>(s);  // row_ror:4
    s = dpp_add<0x128>(s);  // row_ror:8
    s += __shfl_xor(s, 16);
    s += __shfl_xor(s, 32);
    return s;
}

__device__ __forceinline__ float f4c(const float4& v, int j) {
    return j == 0 ? v.x : (j == 1 ? v.y : (j == 2 ? v.z : v.w));
}

// fast squared periodic-Hann: w = 0.5 - 0.5*cos(2*pi*p/1024), via v_cos_f32
__device__ __forceinline__ float w2fast(float p) {
    float w = 0.5f - 0.5f * __cosf(p * (6.28318530717958647692f / 1024.0f));
    return w * w;
}

// ---- kernel 1: per-frame windowed sums, all loads upfront (MLP=14) ------
// sched_barrier(0) after the load block pins all 14 loads BEFORE any compute
// in the post-RA schedule -> forces true 14-deep MLP (compiler was sinking
// them into ~2-deep chains to save VGPRs; R7/R9/R10 VGPR counts prove it).
__global__ __launch_bounds__(WTHREADS) void seg_frames(
    const float* __restrict__ est, const float* __restrict__ tgt,
    float* __restrict__ ws_part, float* __restrict__ ws_bs)
{
    const int tid  = threadIdx.x;
    const int lane = tid & 63;
    const int wave = tid >> 6;
    const int b    = blockIdx.y;
    const int wv   = blockIdx.x * 4 + wave;
    if (wv >= WPR) return;
    const int fb = wv * FR;

    const float* erow = est + (size_t)b * TLEN;
    const float* trow = tgt + (size_t)b * TLEN;

    float pe = 0.f, pt = 0.f;      // plain sums over owned samples (means)

    if (fb >= 4 && fb <= 1868) {
        // ================= fast path =================
        const float4* e4 = (const float4*)erow;
        const float4* t4 = (const float4*)trow;

        // issue ALL 14 loads up front — fully independent, max MLP
        float4 E[7], T[7];
#pragma unroll
        for (int m = 0; m < 7; ++m) {
            int g = 64 * (fb + m) - 128 + lane;
            E[m] = e4[g];
            T[m] = t4[g];
        }
        __builtin_amdgcn_sched_barrier(0);   // pin loads above; keep them live

        // w^2 at positions p = 256q + 4*lane + j  (runs under load latency)
        float w2v[4][4];
#pragma unroll
        for (int q = 0; q < 4; ++q)
#pragma unroll
            for (int j = 0; j < 4; ++j)
                w2v[q][j] = w2fast((float)(256 * q + 4 * lane + j));

        // hop-major: rolling accumulators for 4 frames
        float acc[4][5];
#pragma unroll
        for (int i = 0; i < 4; ++i)
#pragma unroll
            for (int s5 = 0; s5 < 5; ++s5) acc[i][s5] = 0.f;

#pragma unroll
        for (int m = 0; m < 7; ++m) {
            float4 ev4 = E[m], tv4 = T[m];
#pragma unroll
            for (int j = 0; j < 4; ++j) {
                float e = f4c(ev4, j), t = f4c(tv4, j);
                float et = e * t, tt2 = t * t, ee2 = e * e;
#pragma unroll
                for (int i = 0; i < 4; ++i) {
                    if (m - i < 0 || m - i > 3) continue;   // const-folds
                    float w2 = w2v[m - i][j];
                    acc[i][0] = fmaf(w2, et,  acc[i][0]);
                    acc[i][1] = fmaf(w2, tt2, acc[i][1]);
                    acc[i][2] = fmaf(w2, ee2, acc[i][2]);
                    acc[i][3] = fmaf(w2, e,   acc[i][3]);
                    acc[i][4] = fmaf(w2, t,   acc[i][4]);
                }
            }
            if (m < 4) {           // owned samples [256fb-512, 256fb+511]
                pe += (ev4.x + ev4.y) + (ev4.z + ev4.w);
                pt += (tv4.x + tv4.y) + (tv4.z + tv4.w);
            }
        }

#pragma unroll
        for (int i = 0; i < 4; ++i) {
            float s0 = wave_reduce(acc[i][0]);
            float s1 = wave_reduce(acc[i][1]);
            float s2 = wave_reduce(acc[i][2]);
            float s3 = wave_reduce(acc[i][3]);
            float s4 = wave_reduce(acc[i][4]);
            if (lane == 0) {
                float* p = ws_part + (size_t)(b * NF + fb + i) * 5;
                p[0] = s0; p[1] = s1; p[2] = s2; p[3] = s3; p[4] = s4;
            }
        }
    } else {
        // ================= edge path (fb==0 or fb==1872) =================
        int nfr = NF - fb;
        if (nfr > FR) nfr = FR;

        float w2v[4][4];
#pragma unroll
        for (int q = 0; q < 4; ++q)
#pragma unroll
            for (int j = 0; j < 4; ++j)
                w2v[q][j] = w2fast((float)(256 * q + 4 * lane + j));

        for (int i = 0; i < nfr; ++i) {
            int f = fb + i;
            float s_et = 0.f, s_tt = 0.f, s_ee = 0.f, s_e = 0.f, s_t = 0.f;
#pragma unroll
            for (int q = 0; q < 4; ++q)
#pragma unroll
                for (int j = 0; j < 4; ++j) {
                    int s = 256 * f - 512 + 256 * q + 4 * lane + j;
                    int idx = s < 0 ? -s : (s >= TLEN ? 2 * (TLEN - 1) - s : s);
                    float ev = erow[idx], tv = trow[idx];
                    float w2 = w2v[q][j];
                    float et = ev * tv;
                    s_et = fmaf(w2, et,      s_et);
                    s_tt = fmaf(w2, tv * tv, s_tt);
                    s_ee = fmaf(w2, ev * ev, s_ee);
                    s_e  = fmaf(w2, ev, s_e);
                    s_t  = fmaf(w2, tv, s_t);
                }
            s_et = wave_reduce(s_et);
            s_tt = wave_reduce(s_tt);
            s_ee = wave_reduce(s_ee);
            s_e  = wave_reduce(s_e);
            s_t  = wave_reduce(s_t);
            if (lane == 0) {
                float* p = ws_part + (size_t)(b * NF + f) * 5;
                p[0] = s_et; p[1] = s_tt; p[2] = s_ee; p[3] = s_e; p[4] = s_t;
            }
        }

        // owned samples for the means (disjoint from fast waves' coverage)
        const float4* e4 = (const float4*)erow;
        const float4* t4 = (const float4*)trow;
        if (fb == 0) {
            // own [0, 512): 128 float4, 2 per lane
#pragma unroll
            for (int k = 0; k < 2; ++k) {
                float4 ev4 = e4[lane + 64 * k];
                float4 tv4 = t4[lane + 64 * k];
                pe += (ev4.x + ev4.y) + (ev4.z + ev4.w);
                pt += (tv4.x + tv4.y) + (tv4.z + tv4.w);
            }
        } else {
            // own [478720, 480000): 320 float4, 5 per lane
#pragma unroll
            for (int k = 0; k < 5; ++k) {
                int g = 119680 + lane + 64 * k;
                float4 ev4 = e4[g];
                float4 tv4 = t4[g];
                pe += (ev4.x + ev4.y) + (ev4.z + ev4.w);
                pt += (tv4.x + tv4.y) + (tv4.z + tv4.w);
            }
        }
    }

    // per-wave plain-sum partials -> workspace (for the row means)
    pe = wave_reduce(pe);
    pt = wave_reduce(pt);
    if (lane == 0) {
        ws_bs[(0 * NB + b) * WPR + wv] = pe;
        ws_bs[(1 * NB + b) * WPR + wv] = pt;
    }
}

// ------ kernel 2 (fused): recompute row means per block + final loss ------
__global__ __launch_bounds__(WTHREADS) void seg_final(
    const float* __restrict__ ws_part, const float* __restrict__ ws_bs,
    float* __restrict__ out)
{
    const int tid  = threadIdx.x;
    const int lane = tid & 63;
    const int wave = tid >> 6;
    const int idx0 = blockIdx.x * WTHREADS;

    // block spans at most 2 batch rows; 4 waves reduce (sig in {e,t}) x {b0,b1}
    int b0 = idx0 / NF;
    int ilast = idx0 + WTHREADS - 1;
    if (ilast > NB * NF - 1) ilast = NB * NF - 1;
    int b1 = ilast / NF;

    __shared__ float smean[4];   // [which*2 + sig]
    {
        int sig = wave & 1;
        int row = (wave >> 1) ? b1 : b0;
        const float* pbs = ws_bs + (size_t)(sig * NB + row) * WPR;
        float s = 0.f;
        for (int c = lane; c < WPR; c += 64) s += pbs[c];   // 8 iters, L2-hot
        s = wave_reduce(s);
        if (lane == 0) smean[wave] = s * (1.0f / (float)TLEN);
    }
    __syncthreads();

    int idx = idx0 + tid;
    if (idx >= NB * NF) return;
    int b = idx / NF;
    int which = (b == b0) ? 0 : 1;
    float me = smean[which * 2 + 0];
    float mt = smean[which * 2 + 1];

    const float* p = ws_part + (size_t)idx * 5;
    float S_et = p[0], S_tt = p[1], S_ee = p[2], S_e = p[3], S_t = p[4];
    const float W2 = 384.0f;         // sum of squared periodic Hann, exact

    float dot = S_et - mt * S_e - me * S_t + me * mt * W2;
    float tt  = S_tt - 2.0f * mt * S_t + mt * mt * W2;
    float ee  = S_ee - 2.0f * me * S_e + me * me * W2;

    float a     = dot / (tt + 1e-8f);
    float st2   = a * a * tt;
    float en2   = ee - 2.0f * a * dot + st2;
    float ratio = st2 / (en2 + 1e-8f);
    out[idx] = -10.0f * log10f(ratio + 1e-8f);
}

extern "C" void kernel_launch(void* const* d_in, const int* in_sizes, int n_in,
                              void* d_out, int out_size, void* d_ws, size_t ws_size,
                              hipStream_t stream)
{
    const float* est = (const float*)d_in[0];
    const float* tgt = (const float*)d_in[1];
    float* out = (float*)d_out;

    float* ws      = (float*)d_ws;
    float* ws_part = ws;                                   // NB*NF*5   floats
    float* ws_bs   = ws_part + (size_t)NB * NF * 5;        // 2*NB*WPR  floats

    dim3 grid1((WPR + 3) / 4, NB);
    seg_frames<<<grid1, WTHREADS, 0, stream>>>(est, tgt, ws_part, ws_bs);
    dim3 grid2((NB * NF + WTHREADS - 1) / WTHREADS);
    seg_final<<<grid2, WTHREADS, 0, stream>>>(ws_part, ws_bs, out);
}